// Round 10
// baseline (419.268 us; speedup 1.0000x reference)
//
#include <hip/hip_runtime.h>
#include <hip/hip_fp16.h>

#define IN_C 512
#define HID  128
#define HID2 64
#define CPAD 32  // counter padding: 32 ints = 128B per node

typedef __attribute__((ext_vector_type(8))) short short8v;
typedef __attribute__((ext_vector_type(4))) float float4v;

__device__ __forceinline__ unsigned short f2bf(float f) {
  unsigned u = __float_as_uint(f);
  unsigned r = u + 0x7FFF + ((u >> 16) & 1);  // RNE
  return (unsigned short)(r >> 16);
}
__device__ __forceinline__ float bf2f(unsigned short h) {
  return __uint_as_float((unsigned)h << 16);
}
__device__ __forceinline__ uint2 pack4(unsigned short a, unsigned short b,
                                       unsigned short c, unsigned short d) {
  uint2 p;
  p.x = (unsigned)a | ((unsigned)b << 16);
  p.y = (unsigned)c | ((unsigned)d << 16);
  return p;
}
__device__ __forceinline__ void split4(float4 v, uint2& hi, uint2& lo) {
  unsigned short h0 = f2bf(v.x), h1 = f2bf(v.y), h2 = f2bf(v.z), h3 = f2bf(v.w);
  unsigned short l0 = f2bf(v.x - bf2f(h0)), l1 = f2bf(v.y - bf2f(h1));
  unsigned short l2 = f2bf(v.z - bf2f(h2)), l3 = f2bf(v.w - bf2f(h3));
  hi = pack4(h0, h1, h2, h3);
  lo = pack4(l0, l1, l2, l3);
}
// split 8 consecutive f32 (two float4) into one short8v hi + one short8v lo
__device__ __forceinline__ void split8(float4 a, float4 b, short8v& hi, short8v& lo) {
  uint2 h0, l0, h1, l1;
  split4(a, h0, l0);
  split4(b, h1, l1);
  uint4 uh = make_uint4(h0.x, h0.y, h1.x, h1.y);
  uint4 ul = make_uint4(l0.x, l0.y, l1.x, l1.y);
  hi = *(short8v*)&uh;
  lo = *(short8v*)&ul;
}

// ---------------- edge_index dtype detection ----------------
__global__ void k_detect(const unsigned* __restrict__ ei, int* __restrict__ flag) {
  __shared__ int nz;
  if (threadIdx.x == 0) nz = 0;
  __syncthreads();
  if (ei[2 * threadIdx.x + 1] != 0u) atomicOr(&nz, 1);
  __syncthreads();
  if (threadIdx.x == 0) *flag = (nz == 0) ? 1 : 0;  // 1 => int64
}

__device__ __forceinline__ int edge_at(const unsigned* __restrict__ ei, int f, int i) {
  return (int)(f ? ei[2 * (size_t)i] : ei[i]);
}

// ---------------- pre-split W1/W2 into bf16 hi/lo (once, not per block) -------
// layout: w1h[kk][n][8] with kk = k/8  (k = kk*8+j), same for lo / W2.
__global__ void k_wsplit(const float* __restrict__ W1, const float* __restrict__ W2,
                         short* __restrict__ w1h, short* __restrict__ w1l,
                         short* __restrict__ w2h, short* __restrict__ w2l) {
  int tid = blockIdx.x * blockDim.x + threadIdx.x;
  if (tid < 128 * (IN_C / 4)) {  // W1: n=tid/(512/4), k=4*(tid%128)
    int n = tid >> 7, k = (tid & 127) * 4;
    float4 v = *(const float4*)(W1 + (size_t)n * IN_C + k);
    uint2 hi, lo;
    split4(v, hi, lo);
    size_t base = (((size_t)(k >> 3)) * 128 + n) * 8 + (k & 7);
    *(uint2*)(w1h + base) = hi;
    *(uint2*)(w1l + base) = lo;
  } else if (tid < 128 * (IN_C / 4) + 64 * (HID / 4)) {  // W2
    int t = tid - 128 * (IN_C / 4);
    int n = t >> 5, k = (t & 31) * 4;
    float4 v = *(const float4*)(W2 + (size_t)n * HID + k);
    uint2 hi, lo;
    split4(v, hi, lo);
    size_t base = (((size_t)(k >> 3)) * 64 + n) * 8 + (k & 7);
    *(uint2*)(w2h + base) = hi;
    *(uint2*)(w2l + base) = lo;
  }
}

// ---------------- count pass: the ONLY global-atomic kernel ----------------
__global__ void k_cnt(const unsigned* __restrict__ ei, const int* __restrict__ flag,
                      int* __restrict__ cntp, int* __restrict__ rank, int E) {
  int f = *flag;
  int stride = gridDim.x * blockDim.x * 2;
  for (int e = (blockIdx.x * blockDim.x + threadIdx.x) * 2; e < E; e += stride) {
    int c0, c1 = -1;
    if (f) {
      if (e + 1 < E) {
        uint4 v = *(const uint4*)(ei + 2 * (size_t)(E + e));
        c0 = (int)v.x;
        c1 = (int)v.z;
      } else {
        c0 = (int)ei[2 * (size_t)(E + e)];
      }
    } else {
      if (e + 1 < E) {
        uint2 v = *(const uint2*)(ei + (size_t)E + e);
        c0 = (int)v.x;
        c1 = (int)v.y;
      } else {
        c0 = (int)ei[(size_t)E + e];
      }
    }
    rank[e] = atomicAdd(&cntp[c0 * CPAD], 1);
    if (c1 >= 0) rank[e + 1] = atomicAdd(&cntp[c1 * CPAD], 1);
  }
}

// ---------------- hierarchical exclusive scan of cntp (padded) ----------------
__global__ __launch_bounds__(256) void k_scanA(const int* __restrict__ cntp,
                                               int* __restrict__ part,
                                               int* __restrict__ bsum, int N) {
  __shared__ int tmp[256];
  int t = threadIdx.x;
  int idx = blockIdx.x * 1024 + t * 4;
  int4 v;
  v.x = idx + 0 < N ? cntp[(size_t)(idx + 0) * CPAD] : 0;
  v.y = idx + 1 < N ? cntp[(size_t)(idx + 1) * CPAD] : 0;
  v.z = idx + 2 < N ? cntp[(size_t)(idx + 2) * CPAD] : 0;
  v.w = idx + 3 < N ? cntp[(size_t)(idx + 3) * CPAD] : 0;
  int s = v.x + v.y + v.z + v.w;
  tmp[t] = s;
  __syncthreads();
#pragma unroll
  for (int d = 1; d < 256; d <<= 1) {
    int u = (t >= d) ? tmp[t - d] : 0;
    __syncthreads();
    tmp[t] += u;
    __syncthreads();
  }
  int excl = tmp[t] - s;
  int4 o;
  o.x = excl;
  o.y = excl + v.x;
  o.z = excl + v.x + v.y;
  o.w = excl + v.x + v.y + v.z;
  if (idx + 3 < N) {
    *(int4*)(part + idx) = o;
  } else {
    if (idx + 0 < N) part[idx + 0] = o.x;
    if (idx + 1 < N) part[idx + 1] = o.y;
    if (idx + 2 < N) part[idx + 2] = o.z;
    if (idx + 3 < N) part[idx + 3] = o.w;
  }
  if (t == 255) bsum[blockIdx.x] = tmp[255];
}

// rowptr[i] = part[i] + sum(bsum[j] for j < i>>10)  (NB<=49: L1-hot inline scan)
__global__ void k_scanC(const int* __restrict__ part, const int* __restrict__ bsum,
                        int* __restrict__ rowptr, int N, int E, int NB) {
  int i = blockIdx.x * blockDim.x + threadIdx.x;
  if (i < N) {
    int blk = i >> 10;
    int off = 0;
    for (int j = 0; j < blk; j++) off += bsum[j];
    rowptr[i] = part[i] + off;
  }
  if (i == 0) rowptr[N] = E;
}

// ---------------- fill: pure scatter, NO atomics; packed (src, w) ------------
__global__ void k_fill(const unsigned* __restrict__ ei, const int* __restrict__ flag,
                       const float* __restrict__ ew, const int* __restrict__ rowptr,
                       const int* __restrict__ rank, uint2* __restrict__ ep, int E) {
  int f = *flag;
  int stride = gridDim.x * blockDim.x;
  for (int e = blockIdx.x * blockDim.x + threadIdx.x; e < E; e += stride) {
    int r = edge_at(ei, f, e);
    int c = edge_at(ei, f, E + e);
    int p = rowptr[c] + rank[e];
    uint2 m;
    m.x = (unsigned)r;
    m.y = __float_as_uint(ew[e]);
    ep[p] = m;
  }
}

// ---------------- segmented deg-sum -> dinv (quarter-wave per node) ----------
__global__ void k_degsum(const uint2* __restrict__ ep, const int* __restrict__ rowptr,
                         float* __restrict__ dinv, int N) {
  int g = blockIdx.x * blockDim.x + threadIdx.x;
  int node = g >> 4, l = g & 15;
  if (node >= N) return;
  int s = rowptr[node], epd = rowptr[node + 1];
  float sum = 0.f;
  for (int p = s + l; p < epd; p += 16) sum += __uint_as_float(ep[p].y);
  sum += __shfl_xor(sum, 1);
  sum += __shfl_xor(sum, 2);
  sum += __shfl_xor(sum, 4);
  sum += __shfl_xor(sum, 8);
  if (l == 0) {
    float d = sum + 1.0f;  // self loop; always > 0
    float y = rsqrtf(d);
    y = y * (1.5f - 0.5f * d * y * y);  // Newton: ~1 ulp f32
    dinv[node] = y;
  }
}

// ---------------- bake symmetric norm into packed weights (in-place) ----------
__global__ void k_scale(uint2* __restrict__ ep, const int* __restrict__ rowptr,
                        const float* __restrict__ dinv, int N) {
  int g = blockIdx.x * blockDim.x + threadIdx.x;
  int node = g >> 4, l = g & 15;
  if (node >= N) return;
  float dn = dinv[node];
  int s = rowptr[node], epd = rowptr[node + 1];
  for (int p = s + l; p < epd; p += 16) {
    uint2 m = ep[p];
    ep[p].y = __float_as_uint(dinv[m.x] * __uint_as_float(m.y) * dn);
  }
}

// ---------------- GEMM1 (split-bf16 MFMA, NO LDS): h = x @ W1^T ---------------
// 4 waves/block, each wave owns 64 distinct rows x all 128 cols. A-fragments
// read直接 from global (lanes {l,l+16,l+32,l+48} cover one contiguous 128B row
// segment), B-fragments from pre-split W (L2-hot). No barriers at all.
__global__ __launch_bounds__(256) void k_gemm1n(const float* __restrict__ x,
                                                const short* __restrict__ w1h,
                                                const short* __restrict__ w1l,
                                                __half* __restrict__ h, int M) {
  const int lane = threadIdx.x & 63, w = threadIdx.x >> 6;
  const int row0 = blockIdx.x * 256 + w * 64;
  const int kq = lane >> 4, r16 = lane & 15;

  const float* px[4];
#pragma unroll
  for (int mi = 0; mi < 4; mi++) {
    int gr = row0 + mi * 16 + r16;
    if (gr >= M) gr = M - 1;
    px[mi] = x + (size_t)gr * IN_C + kq * 8;
  }

  float4v acc[4][8];
#pragma unroll
  for (int mi = 0; mi < 4; mi++)
#pragma unroll
    for (int nj = 0; nj < 8; nj++) acc[mi][nj] = (float4v)0.f;

  for (int k0 = 0; k0 < IN_C; k0 += 32) {
    short8v ah[4], al[4];
#pragma unroll
    for (int mi = 0; mi < 4; mi++) {
      float4 a = *(const float4*)(px[mi] + k0);
      float4 b = *(const float4*)(px[mi] + k0 + 4);
      split8(a, b, ah[mi], al[mi]);
    }
#pragma unroll
    for (int nj = 0; nj < 8; nj++) {
      size_t gb = (((size_t)(k0 >> 3) + kq) * 128 + nj * 16 + r16) * 8;
      short8v bh = *(const short8v*)(w1h + gb);
      short8v bl = *(const short8v*)(w1l + gb);
#pragma unroll
      for (int mi = 0; mi < 4; mi++) {
        acc[mi][nj] = __builtin_amdgcn_mfma_f32_16x16x32_bf16(ah[mi], bh, acc[mi][nj], 0, 0, 0);
        acc[mi][nj] = __builtin_amdgcn_mfma_f32_16x16x32_bf16(ah[mi], bl, acc[mi][nj], 0, 0, 0);
        acc[mi][nj] = __builtin_amdgcn_mfma_f32_16x16x32_bf16(al[mi], bh, acc[mi][nj], 0, 0, 0);
      }
    }
  }

  // epilogue: D col = lane&15, row = (lane>>4)*4 + b ; store fp16
#pragma unroll
  for (int mi = 0; mi < 4; mi++)
#pragma unroll
    for (int nj = 0; nj < 8; nj++) {
#pragma unroll
      for (int b = 0; b < 4; b++) {
        int grow = row0 + mi * 16 + (lane >> 4) * 4 + b;
        int gcol = nj * 16 + r16;
        if (grow < M) h[(size_t)grow * HID + gcol] = __float2half(acc[mi][nj][b]);
      }
    }
}

// ---------------- GEMM2 (split-bf16 MFMA, NO LDS): h2 = z @ W2^T --------------
__global__ __launch_bounds__(256) void k_gemm2n(const float* __restrict__ z,
                                                const short* __restrict__ w2h,
                                                const short* __restrict__ w2l,
                                                __half* __restrict__ h, int M) {
  const int lane = threadIdx.x & 63, w = threadIdx.x >> 6;
  const int row0 = blockIdx.x * 256 + w * 64;
  const int kq = lane >> 4, r16 = lane & 15;

  const float* pz[4];
#pragma unroll
  for (int mi = 0; mi < 4; mi++) {
    int gr = row0 + mi * 16 + r16;
    if (gr >= M) gr = M - 1;
    pz[mi] = z + (size_t)gr * HID + kq * 8;
  }

  float4v acc[4][4];
#pragma unroll
  for (int mi = 0; mi < 4; mi++)
#pragma unroll
    for (int nj = 0; nj < 4; nj++) acc[mi][nj] = (float4v)0.f;

  for (int k0 = 0; k0 < HID; k0 += 32) {
    short8v ah[4], al[4];
#pragma unroll
    for (int mi = 0; mi < 4; mi++) {
      float4 a = *(const float4*)(pz[mi] + k0);
      float4 b = *(const float4*)(pz[mi] + k0 + 4);
      split8(a, b, ah[mi], al[mi]);
    }
#pragma unroll
    for (int nj = 0; nj < 4; nj++) {
      size_t gb = (((size_t)(k0 >> 3) + kq) * 64 + nj * 16 + r16) * 8;
      short8v bh = *(const short8v*)(w2h + gb);
      short8v bl = *(const short8v*)(w2l + gb);
#pragma unroll
      for (int mi = 0; mi < 4; mi++) {
        acc[mi][nj] = __builtin_amdgcn_mfma_f32_16x16x32_bf16(ah[mi], bh, acc[mi][nj], 0, 0, 0);
        acc[mi][nj] = __builtin_amdgcn_mfma_f32_16x16x32_bf16(ah[mi], bl, acc[mi][nj], 0, 0, 0);
        acc[mi][nj] = __builtin_amdgcn_mfma_f32_16x16x32_bf16(al[mi], bh, acc[mi][nj], 0, 0, 0);
      }
    }
  }

#pragma unroll
  for (int mi = 0; mi < 4; mi++)
#pragma unroll
    for (int nj = 0; nj < 4; nj++) {
#pragma unroll
      for (int b = 0; b < 4; b++) {
        int grow = row0 + mi * 16 + (lane >> 4) * 4 + b;
        int gcol = nj * 16 + r16;
        if (grow < M) h[(size_t)grow * HID2 + gcol] = __float2half(acc[mi][nj][b]);
      }
    }
}

// ---------------- aggregation (pull over CSR, fp16 gather) + bias + PReLU -------
__global__ void k_agg1(const __half* __restrict__ h, const int* __restrict__ rowptr,
                       const uint2* __restrict__ ep, const float* __restrict__ dinv,
                       const float* __restrict__ bias, const float* __restrict__ alpha,
                       float* __restrict__ z, int N) {
  int node = blockIdx.x * 4 + (threadIdx.x >> 6);
  int lane = threadIdx.x & 63;
  if (node >= N) return;
  const __half2* hp = (const __half2*)h;
  float2 acc = make_float2(0.f, 0.f);
  int s = rowptr[node];
  int dg = rowptr[node + 1] - s;
  for (int base = 0; base < dg; base += 64) {
    int k = base + lane;
    uint2 m = make_uint2(0u, 0u);
    if (k < dg) m = ep[s + k];
    int cnt = min(64, dg - base);
#pragma unroll 4
    for (int j = 0; j < cnt; j++) {
      int src = __shfl((int)m.x, j);
      float wv = __shfl(__uint_as_float(m.y), j);
      float2 v = __half22float2(hp[(size_t)src * 64 + lane]);
      acc.x += wv * v.x;
      acc.y += wv * v.y;
    }
  }
  float di = dinv[node];
  float sw = di * di;
  float2 v = __half22float2(hp[(size_t)node * 64 + lane]);
  acc.x += sw * v.x;
  acc.y += sw * v.y;
  acc.x += bias[lane * 2];
  acc.y += bias[lane * 2 + 1];
  float a0 = alpha[lane * 2], a1 = alpha[lane * 2 + 1];
  acc.x = acc.x >= 0.f ? acc.x : a0 * acc.x;
  acc.y = acc.y >= 0.f ? acc.y : a1 * acc.y;
  ((float2*)z)[(size_t)node * 64 + lane] = acc;
}

__global__ void k_agg2(const __half* __restrict__ h, const int* __restrict__ rowptr,
                       const uint2* __restrict__ ep, const float* __restrict__ dinv,
                       const float* __restrict__ bias, const float* __restrict__ alpha,
                       float* __restrict__ out, int N) {
  int node = blockIdx.x * 4 + (threadIdx.x >> 6);
  int lane = threadIdx.x & 63;
  if (node >= N) return;
  float acc = 0.f;
  int s = rowptr[node];
  int dg = rowptr[node + 1] - s;
  for (int base = 0; base < dg; base += 64) {
    int k = base + lane;
    uint2 m = make_uint2(0u, 0u);
    if (k < dg) m = ep[s + k];
    int cnt = min(64, dg - base);
#pragma unroll 4
    for (int j = 0; j < cnt; j++) {
      int src = __shfl((int)m.x, j);
      float wv = __shfl(__uint_as_float(m.y), j);
      acc += wv * __half2float(h[(size_t)src * HID2 + lane]);
    }
  }
  float di = dinv[node];
  acc += di * di * __half2float(h[(size_t)node * HID2 + lane]);
  acc += bias[lane];
  float a = alpha[lane];
  acc = acc >= 0.f ? acc : a * acc;
  out[(size_t)node * HID2 + lane] = acc;
}

extern "C" void kernel_launch(void* const* d_in, const int* in_sizes, int n_in,
                              void* d_out, int out_size, void* d_ws, size_t ws_size,
                              hipStream_t stream) {
  const float* x = (const float*)d_in[0];
  const unsigned* ei = (const unsigned*)d_in[1];
  const float* ew = (const float*)d_in[2];
  const float* W1 = (const float*)d_in[3];
  const float* b1 = (const float*)d_in[4];
  const float* a1 = (const float*)d_in[5];
  const float* W2 = (const float*)d_in[6];
  const float* b2 = (const float*)d_in[7];
  const float* a2 = (const float*)d_in[8];
  float* out = (float*)d_out;

  const int N = in_sizes[0] / IN_C;
  const int E = in_sizes[2];
  const int NB = (N + 1023) / 1024;

  char* w = (char*)d_ws;
  auto alloc = [&](size_t bytes) -> void* {
    void* p = (void*)w;
    w += (bytes + 255) / 256 * 256;
    return p;
  };
  int* flag = (int*)alloc(4);
  int* cntp = (int*)alloc((size_t)N * CPAD * 4);
  int* rank = (int*)alloc((size_t)E * 4);
  float* dinv = (float*)alloc((size_t)N * 4);
  int* rowptr = (int*)alloc((size_t)(N + 1) * 4);
  int* part = (int*)alloc((size_t)N * 4);
  int* bsum = (int*)alloc(256 * 4);
  uint2* ep = (uint2*)alloc((size_t)E * 8);  // packed (src, w)
  short* w1h = (short*)alloc((size_t)HID * IN_C * 2);
  short* w1l = (short*)alloc((size_t)HID * IN_C * 2);
  short* w2h = (short*)alloc((size_t)HID2 * HID * 2);
  short* w2l = (short*)alloc((size_t)HID2 * HID * 2);
  __half* h1 = (__half*)alloc((size_t)N * HID * 2);
  float* z1 = (float*)alloc((size_t)N * HID * 4);
  __half* h2 = (__half*)alloc((size_t)N * HID2 * 2);

  hipMemsetAsync(cntp, 0, (size_t)N * CPAD * 4, stream);

  k_detect<<<1, 256, 0, stream>>>(ei, flag);
  k_wsplit<<<(128 * (IN_C / 4) + 64 * (HID / 4) + 255) / 256, 256, 0, stream>>>(
      W1, W2, w1h, w1l, w2h, w2l);
  k_cnt<<<1024, 256, 0, stream>>>(ei, flag, cntp, rank, E);
  k_scanA<<<NB, 256, 0, stream>>>(cntp, part, bsum, N);
  k_scanC<<<(N + 255) / 256, 256, 0, stream>>>(part, bsum, rowptr, N, E, NB);
  k_fill<<<1024, 256, 0, stream>>>(ei, flag, ew, rowptr, rank, ep, E);
  k_degsum<<<(N * 16 + 255) / 256, 256, 0, stream>>>(ep, rowptr, dinv, N);
  k_scale<<<(N * 16 + 255) / 256, 256, 0, stream>>>(ep, rowptr, dinv, N);

  k_gemm1n<<<(N + 255) / 256, 256, 0, stream>>>(x, w1h, w1l, h1, N);
  k_agg1<<<(N + 3) / 4, 256, 0, stream>>>(h1, rowptr, ep, dinv, b1, a1, z1, N);
  k_gemm2n<<<(N + 255) / 256, 256, 0, stream>>>(z1, w2h, w2l, h2, N);
  k_agg2<<<(N + 3) / 4, 256, 0, stream>>>(h2, rowptr, ep, dinv, b2, a2, out, N);
}